// Round 9
// baseline (417.436 us; speedup 1.0000x reference)
//
#include <hip/hip_runtime.h>
#include <math.h>

constexpr int B   = 2;
constexpr int N   = 2048;
constexpr int HID = 768;
constexpr int H   = 12;
constexpr int D   = 64;
constexpr int M   = B * N;
constexpr int QKV_ELEMS = B * H * N * D;   // 3,145,728 elems per tensor
constexpr int SE  = 4096;                  // extended rel-table rows

typedef __attribute__((ext_vector_type(8))) short s8v;            // 8 x bf16
typedef __attribute__((ext_vector_type(8))) unsigned short u8v;   // 8 x u16
typedef __attribute__((ext_vector_type(4))) float f4v;            // 4 x f32
typedef unsigned short ushort_t;

__device__ __forceinline__ float bf2f(short u) {
    union { unsigned int i; float f; } v;
    v.i = ((unsigned int)(unsigned short)u) << 16;
    return v.f;
}
__device__ __forceinline__ unsigned short f2bf(float f) {
    union { float f; unsigned int i; } v; v.f = f;
    unsigned int r = v.i + 0x7fff + ((v.i >> 16) & 1);   // RNE
    return (unsigned short)(r >> 16);
}
__device__ __forceinline__ f4v mfma16(s8v a, s8v b, f4v c) {
    return __builtin_amdgcn_mfma_f32_16x16x32_bf16(a, b, c, 0, 0, 0);
}
__device__ __forceinline__ void gl2lds16(const void* g, void* l) {
    __builtin_amdgcn_global_load_lds(
        (const __attribute__((address_space(1))) void*)g,
        (__attribute__((address_space(3))) void*)l, 16, 0, 0);
}
__device__ __forceinline__ u8v cvt8(const float* src) {
    float4 a = *(const float4*)src;
    float4 b = *(const float4*)(src + 4);
    u8v o;
    o[0] = f2bf(a.x); o[1] = f2bf(a.y); o[2] = f2bf(a.z); o[3] = f2bf(a.w);
    o[4] = f2bf(b.x); o[5] = f2bf(b.y); o[6] = f2bf(b.z); o[7] = f2bf(b.w);
    return o;
}
// extended-table source row: s in [0,4096) -> tv = s-2049
//   tv<0 (s<=2048): src = s-1 (s==0 -> 0);  tv>=0: src = s-2049
__device__ __forceinline__ int esrc(int s) {
    return (s == 0) ? 0 : ((s <= 2048) ? (s - 1) : (s - 2049));
}

// ---------------------------------------------------------------------------
// Convert: hs->hsb bf16, W->Wb bf16, r_emb->rese (extended, [h][s][d] bf16),
// r_bias->rbe (extended, [h][s] f32).
// ---------------------------------------------------------------------------
constexpr int CVT_C0 = M * HID / 8;                   // 393216  hsb
constexpr int CVT_C1 = CVT_C0 + 3 * HID * HID / 8;    // 614400  Wb
constexpr int CVT_C2 = CVT_C1 + H * SE * D / 8;       // 1007616 rese
constexpr int CVT_C3 = CVT_C2 + H * SE;               // 1056768 rbe

__global__ __launch_bounds__(256) void convert_kernel(
    const float* __restrict__ hs,
    const float* __restrict__ Wq, const float* __restrict__ Wk,
    const float* __restrict__ Wv,
    const float* __restrict__ r_emb, const float* __restrict__ r_bias,
    ushort_t* __restrict__ hsb, ushort_t* __restrict__ Wb,
    ushort_t* __restrict__ rese, float* __restrict__ rbe)
{
    const int idx = blockIdx.x * 256 + threadIdx.x;
    if (idx < CVT_C0) {
        *(u8v*)&hsb[(size_t)idx * 8] = cvt8(&hs[(size_t)idx * 8]);
    } else if (idx < CVT_C1) {
        const int j  = idx - CVT_C0;
        const int z  = j / (HID * HID / 8);
        const int jj = j - z * (HID * HID / 8);
        const float* W = (z == 0) ? Wq : ((z == 1) ? Wk : Wv);
        *(u8v*)&Wb[(size_t)z * HID * HID + (size_t)jj * 8] =
            cvt8(&W[(size_t)jj * 8]);
    } else if (idx < CVT_C2) {
        const int k  = idx - CVT_C1;           // (h, s, d8)
        const int d0 = (k & 7) * 8;
        const int s  = (k >> 3) & (SE - 1);
        const int h  = k >> 15;
        const int r  = esrc(s);
        *(u8v*)&rese[(size_t)k * 8] = cvt8(&r_emb[((size_t)r * H + h) * D + d0]);
    } else if (idx < CVT_C3) {
        const int j = idx - CVT_C2;
        const int h = j >> 12;
        const int s = j & (SE - 1);
        rbe[j] = r_bias[(size_t)esrc(s) * H + h];
    }
}

// ---------------------------------------------------------------------------
// QKV projection, bf16 MFMA (unchanged).
// ---------------------------------------------------------------------------
__global__ __launch_bounds__(256) void qkv_mfma_kernel(
    const ushort_t* __restrict__ hsb, const ushort_t* __restrict__ Wb,
    const float* __restrict__ bq, const float* __restrict__ bk,
    const float* __restrict__ bv,
    ushort_t* __restrict__ Qo, ushort_t* __restrict__ Ko,
    ushort_t* __restrict__ Vt)
{
    const int z  = blockIdx.z;
    const int m0 = blockIdx.x * 128;
    const int o0 = blockIdx.y * 128;
    const ushort_t* Wz = Wb + (size_t)z * HID * HID;
    const float* bias = (z == 0) ? bq : ((z == 1) ? bk : bv);

    __shared__ ushort_t Ah[128 * 64];
    __shared__ ushort_t Wh[128 * 64];

    const int t    = threadIdx.x;
    const int lane = t & 63;
    const int w    = t >> 6;
    const int quad = lane >> 4;
    const int col  = lane & 15;
    const int x0   = (w >> 1) * 64;
    const int y0   = (w & 1) * 64;

    const ushort_t* Xs = (z == 2) ? Ah : Wh;
    const ushort_t* Ys = (z == 2) ? Wh : Ah;

    f4v acc[16];
    #pragma unroll
    for (int i = 0; i < 16; i++) acc[i] = (f4v){0.f, 0.f, 0.f, 0.f};

    const int srow = w * 32 + (lane >> 3);
    const int scol = lane & 7;

    for (int k0 = 0; k0 < HID; k0 += 64) {
        __syncthreads();
        #pragma unroll
        for (int e = 0; e < 4; e++) {
            const int row = srow + e * 8;
            const int c8  = scol ^ (row & 7);
            gl2lds16(&hsb[(size_t)(m0 + row) * HID + k0 + c8 * 8],
                     (void*)&Ah[(w * 32 + e * 8) * 64]);
            gl2lds16(&Wz[(size_t)(o0 + row) * HID + k0 + c8 * 8],
                     (void*)&Wh[(w * 32 + e * 8) * 64]);
        }
        __syncthreads();

        #pragma unroll
        for (int ks = 0; ks < 2; ks++) {
            s8v xf[4], yf[4];
            #pragma unroll
            for (int tt = 0; tt < 4; tt++) {
                const int xr  = x0 + tt * 16 + col;
                const int xc8 = (ks * 4 + quad) ^ (xr & 7);
                xf[tt] = *(const s8v*)&Xs[xr * 64 + xc8 * 8];
                const int yr  = y0 + tt * 16 + col;
                const int yc8 = (ks * 4 + quad) ^ (yr & 7);
                yf[tt] = *(const s8v*)&Ys[yr * 64 + yc8 * 8];
            }
            #pragma unroll
            for (int xt = 0; xt < 4; xt++)
                #pragma unroll
                for (int yt = 0; yt < 4; yt++)
                    acc[xt * 4 + yt] = mfma16(xf[xt], yf[yt], acc[xt * 4 + yt]);
        }
    }

    if (z < 2) {
        ushort_t* dst = (z == 0) ? Qo : Ko;
        #pragma unroll
        for (int xt = 0; xt < 4; xt++) {
            const int ob = o0 + x0 + xt * 16 + quad * 4;
            const int h  = ob >> 6;
            const int d0 = ob & 63;
            const float4 bv4 = *(const float4*)&bias[ob];
            #pragma unroll
            for (int yt = 0; yt < 4; yt++) {
                const int m  = m0 + y0 + yt * 16 + col;
                const int bb = m >> 11;
                const int ii = m & (N - 1);
                f4v a = acc[xt * 4 + yt];
                ushort4 pk;
                pk.x = f2bf(a[0] + bv4.x);
                pk.y = f2bf(a[1] + bv4.y);
                pk.z = f2bf(a[2] + bv4.z);
                pk.w = f2bf(a[3] + bv4.w);
                *(ushort4*)&dst[(((size_t)bb * H + h) * N + ii) * D + d0] = pk;
            }
        }
    } else {
        #pragma unroll
        for (int yt = 0; yt < 4; yt++) {
            const int o = o0 + y0 + yt * 16 + col;
            const int h = o >> 6;
            const int d = o & 63;
            const float bs = bias[o];
            #pragma unroll
            for (int xt = 0; xt < 4; xt++) {
                const int m  = m0 + x0 + xt * 16 + quad * 4;
                const int bb = m >> 11;
                const int ib = m & (N - 1);
                f4v a = acc[xt * 4 + yt];
                ushort4 pk;
                pk.x = f2bf(a[0] + bs);
                pk.y = f2bf(a[1] + bs);
                pk.z = f2bf(a[2] + bs);
                pk.w = f2bf(a[3] + bs);
                *(ushort4*)&Vt[(((size_t)bb * H + h) * D + d) * N + ib] = pk;
            }
        }
    }
}

// ---------------------------------------------------------------------------
// Fused relative attention v6: TRANSPOSED MFMA chain (S^T: q in lane&15),
// barrier-free (all fragments from global; SbA/SbB cover both rel-shift
// branches; LDS strictly wave-private). DS ops/wave-tile: 10 ds_write_b64
// (Sb) + 16 u16 gather + 4 ds_write_b64 (P) + 2 ds_read_b128 (P).
// Plain launch bounds: rounds 5/6 proved VGPR caps => spill collapse.
// grid: (N/64, H, B)  block: 256 (4 waves), wave w owns q rows 16w..16w+15.
// ---------------------------------------------------------------------------
constexpr int SBS = 84;      // SbA/SbB row stride (elems)
constexpr int PSS = 72;      // PsT row stride (elems)

__global__ __launch_bounds__(256) void attn_mfma_kernel(
    const ushort_t* __restrict__ Qb, const ushort_t* __restrict__ Kb,
    const ushort_t* __restrict__ Vt, const ushort_t* __restrict__ rese,
    const float* __restrict__ rbe, const float* __restrict__ rwb_g,
    float* __restrict__ out)
{
    const int i0 = blockIdx.x * 64;
    const int h  = blockIdx.y;
    const int b  = blockIdx.z;
    const int bh = b * H + h;

    const ushort_t* Qbh   = Qb + (size_t)bh * N * D;
    const ushort_t* Kbh   = Kb + (size_t)bh * N * D;
    const ushort_t* Vbh   = Vt + (size_t)bh * D * N;    // [d][n]
    const ushort_t* reseh = rese + (size_t)h * SE * D;  // [s][d] extended
    const float*    rbeh  = rbe + (size_t)h * SE;

    // LDS (all wave-private): SbA 4x1344 | SbB 4x1344 | PsT 4x1152 elems
    __shared__ __align__(16) char smem[30720];

    const int t    = threadIdx.x;
    const int lane = t & 63;
    const int w    = t >> 6;
    const int quad = lane >> 4;
    const int col  = lane & 15;

    ushort_t* SbA = (ushort_t*)smem + w * (16 * SBS);
    ushort_t* SbB = (ushort_t*)(smem + 10752) + w * (16 * SBS);
    ushort_t* PsT = (ushort_t*)(smem + 21504) + w * (16 * PSS);

    // ---- q B-fragments (n = col -> q row R0+col) ----
    const int qg    = i0 + 16 * w + col;            // this lane's q row
    const int qg1   = min(qg + 1, N - 1);           // +1 row (branch B)
    s8v qw[2], qrB[2], qbB[2];
    #pragma unroll
    for (int ks = 0; ks < 2; ks++) {
        qrB[ks] = *(const s8v*)&Qbh[(size_t)qg * D + ks * 32 + quad * 8];
        qbB[ks] = *(const s8v*)&Qbh[(size_t)qg1 * D + ks * 32 + quad * 8];
        float4 ra  = *(const float4*)&rwb_g[h * D + ks * 32 + quad * 8];
        float4 rb4 = *(const float4*)&rwb_g[h * D + ks * 32 + quad * 8 + 4];
        const float rv[8] = {ra.x, ra.y, ra.z, ra.w, rb4.x, rb4.y, rb4.z, rb4.w};
        s8v qq;
        #pragma unroll
        for (int j = 0; j < 8; j++)
            qq[j] = (short)f2bf(bf2f(qrB[ks][j]) + rv[j]);
        qw[ks] = qq;
    }

    f4v Oacc[4];
    #pragma unroll
    for (int dt = 0; dt < 4; dt++) Oacc[dt] = (f4v){0.f, 0.f, 0.f, 0.f};
    float lacc = 0.f;

    // extended-table base: row = sb0 + tt*16 + col, sb0 = j0 + c0s
    const int c0s = -i0 - 16 * w + 2032;
    const float ESC = 0.18033688011112042f;   // 0.125 * log2(e)

    #pragma unroll 1
    for (int s = 0; s < 32; ++s) {
        const int j0  = s * 64;
        const int sb0 = j0 + c0s;

        // ---- K fragments (A-operand: m = col -> key row) ----
        s8v kb[4][2];
        #pragma unroll
        for (int tile = 0; tile < 4; tile++)
            #pragma unroll
            for (int ks = 0; ks < 2; ks++)
                kb[tile][ks] = *(const s8v*)
                    &Kbh[(size_t)(j0 + tile * 16 + col) * D + ks * 32 + quad * 8];

        // ---- rese fragments (A-operand: m = col -> table row) + rbe ----
        s8v rf[5][2];
        float4 rbv[5];
        #pragma unroll
        for (int tt = 0; tt < 5; tt++) {
            const int row = sb0 + tt * 16 + col;
            #pragma unroll
            for (int ks = 0; ks < 2; ks++)
                rf[tt][ks] = *(const s8v*)&reseh[(size_t)row * D + ks * 32 + quad * 8];
            rbv[tt] = *(const float4*)&rbeh[sb0 + tt * 16 + quad * 4];
        }

        // ---- AC (S^T): acc[tile] holds (key = tile*16+quad*4+reg, q = col) --
        f4v acc[4];
        #pragma unroll
        for (int tile = 0; tile < 4; tile++) {
            acc[tile] = mfma16(kb[tile][0], qw[0], (f4v){0.f, 0.f, 0.f, 0.f});
            acc[tile] = mfma16(kb[tile][1], qw[1], acc[tile]);
        }

        // ---- SbA/SbB (v = tt*16+quad*4+reg, q = col) -> b64 LDS writes ----
        #pragma unroll
        for (int tt = 0; tt < 5; tt++) {
            f4v sa = mfma16(rf[tt][0], qrB[0], (f4v){0.f, 0.f, 0.f, 0.f});
            sa = mfma16(rf[tt][1], qrB[1], sa);
            f4v sb = mfma16(rf[tt][0], qbB[0], (f4v){0.f, 0.f, 0.f, 0.f});
            sb = mfma16(rf[tt][1], qbB[1], sb);
            ushort4 pa, pb;
            pa.x = f2bf(sa[0] + rbv[tt].x); pa.y = f2bf(sa[1] + rbv[tt].y);
            pa.z = f2bf(sa[2] + rbv[tt].z); pa.w = f2bf(sa[3] + rbv[tt].w);
            pb.x = f2bf(sb[0] + rbv[tt].x); pb.y = f2bf(sb[1] + rbv[tt].y);
            pb.z = f2bf(sb[2] + rbv[tt].z); pb.w = f2bf(sb[3] + rbv[tt].w);
            const int ro = col * SBS + tt * 16 + quad * 4;
            *(ushort4*)&SbA[ro] = pa;
            *(ushort4*)&SbB[ro] = pb;
        }

        // ---- V fragments (A-operand for PV: m = col -> d row) ----
        s8v vfr[4][2];
        #pragma unroll
        for (int dt = 0; dt < 4; dt++)
            #pragma unroll
            for (int ks = 0; ks < 2; ks++)
                vfr[dt][ks] = *(const s8v*)
                    &Vbh[(size_t)(dt * 16 + col) * N + j0 + ks * 32 + quad * 8];

        __asm__ volatile("s_waitcnt lgkmcnt(0)" ::: "memory");

        // ---- gather (rel_shift) + no-max softmax + PsT b64 writes ----
        #pragma unroll
        for (int tile = 0; tile < 4; tile++) {
            const int cbase = tile * 16 + quad * 4;
            float pv[4];
            #pragma unroll
            for (int reg = 0; reg < 4; reg++) {
                const int c    = cbase + reg;
                const int trel = j0 + c - qg;
                const int iv   = c - col + 16;     // [1,79]
                const ushort_t* src = (trel >= 2)
                    ? &SbB[col * SBS + iv - 1] : &SbA[col * SBS + iv];
                float bd = (trel == 1) ? 0.f : bf2f((short)*src);
                const float e = __builtin_exp2f((acc[tile][reg] + bd) * ESC);
                pv[reg] = e;
                lacc += e;
            }
            ushort4 pp;
            pp.x = f2bf(pv[0]); pp.y = f2bf(pv[1]);
            pp.z = f2bf(pv[2]); pp.w = f2bf(pv[3]);
            *(ushort4*)&PsT[col * PSS + cbase] = pp;
        }
        __asm__ volatile("s_waitcnt lgkmcnt(0)" ::: "memory");

        // ---- PV: O^T[d][q] += V^T-frag x P^T-frag ----
        s8v pf[2];
        #pragma unroll
        for (int ks = 0; ks < 2; ks++)
            pf[ks] = *(s8v*)&PsT[col * PSS + ks * 32 + quad * 8];
        #pragma unroll
        for (int dt = 0; dt < 4; dt++) {
            Oacc[dt] = mfma16(vfr[dt][0], pf[0], Oacc[dt]);
            Oacc[dt] = mfma16(vfr[dt][1], pf[1], Oacc[dt]);
        }
    }

    // ---- final l reduction (quads share q=col) + epilogue ----
    lacc += __shfl_xor(lacc, 16, 64);
    lacc += __shfl_xor(lacc, 32, 64);
    const float inv = 1.f / lacc;
    const size_t base = ((size_t)b * N + qg) * HID + h * D;
    #pragma unroll
    for (int dt = 0; dt < 4; dt++) {
        float4 o4;
        o4.x = Oacc[dt][0] * inv;
        o4.y = Oacc[dt][1] * inv;
        o4.z = Oacc[dt][2] * inv;
        o4.w = Oacc[dt][3] * inv;
        *(float4*)&out[base + dt * 16 + quad * 4] = o4;
    }
}

// ---------------------------------------------------------------------------
extern "C" void kernel_launch(void* const* d_in, const int* in_sizes, int n_in,
                              void* d_out, int out_size, void* d_ws, size_t ws_size,
                              hipStream_t stream)
{
    (void)in_sizes; (void)n_in; (void)out_size; (void)ws_size;
    const float* hs   = (const float*)d_in[0];
    const float* remb = (const float*)d_in[1];
    const float* rwb  = (const float*)d_in[2];
    const float* rb   = (const float*)d_in[3];
    const float* Wq   = (const float*)d_in[4];
    const float* bq   = (const float*)d_in[5];
    const float* Wk   = (const float*)d_in[6];
    const float* bk   = (const float*)d_in[7];
    const float* Wv   = (const float*)d_in[8];
    const float* bv   = (const float*)d_in[9];
    float* out = (float*)d_out;

    ushort_t* Qb   = (ushort_t*)d_ws;
    ushort_t* Kb   = Qb + QKV_ELEMS;
    ushort_t* Vt   = Kb + QKV_ELEMS;
    ushort_t* rese = Vt + QKV_ELEMS;              // H*SE*D = 3,145,728
    float*    rbe  = (float*)(rese + H * SE * D); // H*SE
    ushort_t* hsb  = (ushort_t*)(rbe + H * SE);
    ushort_t* Wb   = hsb + (size_t)M * HID;

    convert_kernel<<<CVT_C3 / 256, 256, 0, stream>>>(
        hs, Wq, Wk, Wv, remb, rb, hsb, Wb, rese, rbe);
    qkv_mfma_kernel<<<dim3(M / 128, HID / 128, 3), 256, 0, stream>>>(
        hsb, Wb, bq, bk, bv, Qb, Kb, Vt);
    attn_mfma_kernel<<<dim3(N / 64, H, B), 256, 0, stream>>>(
        Qb, Kb, Vt, rese, rbe, rwb, out);
}

// Round 10
// 404.476 us; speedup vs baseline: 1.0320x; 1.0320x over previous
//
#include <hip/hip_runtime.h>
#include <math.h>

constexpr int B   = 2;
constexpr int N   = 2048;
constexpr int HID = 768;
constexpr int H   = 12;
constexpr int D   = 64;
constexpr int M   = B * N;
constexpr int QKV_ELEMS = B * H * N * D;   // 3,145,728 elems per tensor
constexpr int SE  = 4096;                  // extended rel-table rows

typedef __attribute__((ext_vector_type(8))) short s8v;            // 8 x bf16
typedef __attribute__((ext_vector_type(8))) unsigned short u8v;   // 8 x u16
typedef __attribute__((ext_vector_type(4))) float f4v;            // 4 x f32
typedef unsigned short ushort_t;
typedef unsigned long long ull_t;

__device__ __forceinline__ float bf2f(short u) {
    union { unsigned int i; float f; } v;
    v.i = ((unsigned int)(unsigned short)u) << 16;
    return v.f;
}
__device__ __forceinline__ unsigned short f2bf(float f) {
    union { float f; unsigned int i; } v; v.f = f;
    unsigned int r = v.i + 0x7fff + ((v.i >> 16) & 1);   // RNE
    return (unsigned short)(r >> 16);
}
__device__ __forceinline__ f4v mfma16(s8v a, s8v b, f4v c) {
    return __builtin_amdgcn_mfma_f32_16x16x32_bf16(a, b, c, 0, 0, 0);
}
__device__ __forceinline__ void gl2lds16(const void* g, void* l) {
    __builtin_amdgcn_global_load_lds(
        (const __attribute__((address_space(1))) void*)g,
        (__attribute__((address_space(3))) void*)l, 16, 0, 0);
}
__device__ __forceinline__ u8v cvt8(const float* src) {
    float4 a = *(const float4*)src;
    float4 b = *(const float4*)(src + 4);
    u8v o;
    o[0] = f2bf(a.x); o[1] = f2bf(a.y); o[2] = f2bf(a.z); o[3] = f2bf(a.w);
    o[4] = f2bf(b.x); o[5] = f2bf(b.y); o[6] = f2bf(b.z); o[7] = f2bf(b.w);
    return o;
}
// extended-table source row: s in [0,4096) -> tv = s-2049
__device__ __forceinline__ int esrc(int s) {
    return (s == 0) ? 0 : ((s <= 2048) ? (s - 1) : (s - 2049));
}

// ---------------------------------------------------------------------------
// Convert: hs->hsb bf16, W->Wb bf16, r_emb->rese (extended [h][s][d] bf16),
// r_bias->rbe (extended [h][s] f32).  (unchanged)
// ---------------------------------------------------------------------------
constexpr int CVT_C0 = M * HID / 8;
constexpr int CVT_C1 = CVT_C0 + 3 * HID * HID / 8;
constexpr int CVT_C2 = CVT_C1 + H * SE * D / 8;
constexpr int CVT_C3 = CVT_C2 + H * SE;

__global__ __launch_bounds__(256) void convert_kernel(
    const float* __restrict__ hs,
    const float* __restrict__ Wq, const float* __restrict__ Wk,
    const float* __restrict__ Wv,
    const float* __restrict__ r_emb, const float* __restrict__ r_bias,
    ushort_t* __restrict__ hsb, ushort_t* __restrict__ Wb,
    ushort_t* __restrict__ rese, float* __restrict__ rbe)
{
    const int idx = blockIdx.x * 256 + threadIdx.x;
    if (idx < CVT_C0) {
        *(u8v*)&hsb[(size_t)idx * 8] = cvt8(&hs[(size_t)idx * 8]);
    } else if (idx < CVT_C1) {
        const int j  = idx - CVT_C0;
        const int z  = j / (HID * HID / 8);
        const int jj = j - z * (HID * HID / 8);
        const float* W = (z == 0) ? Wq : ((z == 1) ? Wk : Wv);
        *(u8v*)&Wb[(size_t)z * HID * HID + (size_t)jj * 8] =
            cvt8(&W[(size_t)jj * 8]);
    } else if (idx < CVT_C2) {
        const int k  = idx - CVT_C1;           // (h, s, d8)
        const int d0 = (k & 7) * 8;
        const int s  = (k >> 3) & (SE - 1);
        const int h  = k >> 15;
        const int r  = esrc(s);
        *(u8v*)&rese[(size_t)k * 8] = cvt8(&r_emb[((size_t)r * H + h) * D + d0]);
    } else if (idx < CVT_C3) {
        const int j = idx - CVT_C2;
        const int h = j >> 12;
        const int s = j & (SE - 1);
        rbe[j] = r_bias[(size_t)esrc(s) * H + h];
    }
}

// ---------------------------------------------------------------------------
// QKV projection, bf16 MFMA (unchanged).
// ---------------------------------------------------------------------------
__global__ __launch_bounds__(256) void qkv_mfma_kernel(
    const ushort_t* __restrict__ hsb, const ushort_t* __restrict__ Wb,
    const float* __restrict__ bq, const float* __restrict__ bk,
    const float* __restrict__ bv,
    ushort_t* __restrict__ Qo, ushort_t* __restrict__ Ko,
    ushort_t* __restrict__ Vt)
{
    const int z  = blockIdx.z;
    const int m0 = blockIdx.x * 128;
    const int o0 = blockIdx.y * 128;
    const ushort_t* Wz = Wb + (size_t)z * HID * HID;
    const float* bias = (z == 0) ? bq : ((z == 1) ? bk : bv);

    __shared__ ushort_t Ah[128 * 64];
    __shared__ ushort_t Wh[128 * 64];

    const int t    = threadIdx.x;
    const int lane = t & 63;
    const int w    = t >> 6;
    const int quad = lane >> 4;
    const int col  = lane & 15;
    const int x0   = (w >> 1) * 64;
    const int y0   = (w & 1) * 64;

    const ushort_t* Xs = (z == 2) ? Ah : Wh;
    const ushort_t* Ys = (z == 2) ? Wh : Ah;

    f4v acc[16];
    #pragma unroll
    for (int i = 0; i < 16; i++) acc[i] = (f4v){0.f, 0.f, 0.f, 0.f};

    const int srow = w * 32 + (lane >> 3);
    const int scol = lane & 7;

    for (int k0 = 0; k0 < HID; k0 += 64) {
        __syncthreads();
        #pragma unroll
        for (int e = 0; e < 4; e++) {
            const int row = srow + e * 8;
            const int c8  = scol ^ (row & 7);
            gl2lds16(&hsb[(size_t)(m0 + row) * HID + k0 + c8 * 8],
                     (void*)&Ah[(w * 32 + e * 8) * 64]);
            gl2lds16(&Wz[(size_t)(o0 + row) * HID + k0 + c8 * 8],
                     (void*)&Wh[(w * 32 + e * 8) * 64]);
        }
        __syncthreads();

        #pragma unroll
        for (int ks = 0; ks < 2; ks++) {
            s8v xf[4], yf[4];
            #pragma unroll
            for (int tt = 0; tt < 4; tt++) {
                const int xr  = x0 + tt * 16 + col;
                const int xc8 = (ks * 4 + quad) ^ (xr & 7);
                xf[tt] = *(const s8v*)&Xs[xr * 64 + xc8 * 8];
                const int yr  = y0 + tt * 16 + col;
                const int yc8 = (ks * 4 + quad) ^ (yr & 7);
                yf[tt] = *(const s8v*)&Ys[yr * 64 + yc8 * 8];
            }
            #pragma unroll
            for (int xt = 0; xt < 4; xt++)
                #pragma unroll
                for (int yt = 0; yt < 4; yt++)
                    acc[xt * 4 + yt] = mfma16(xf[xt], yf[yt], acc[xt * 4 + yt]);
        }
    }

    if (z < 2) {
        ushort_t* dst = (z == 0) ? Qo : Ko;
        #pragma unroll
        for (int xt = 0; xt < 4; xt++) {
            const int ob = o0 + x0 + xt * 16 + quad * 4;
            const int h  = ob >> 6;
            const int d0 = ob & 63;
            const float4 bv4 = *(const float4*)&bias[ob];
            #pragma unroll
            for (int yt = 0; yt < 4; yt++) {
                const int m  = m0 + y0 + yt * 16 + col;
                const int bb = m >> 11;
                const int ii = m & (N - 1);
                f4v a = acc[xt * 4 + yt];
                ushort4 pk;
                pk.x = f2bf(a[0] + bv4.x);
                pk.y = f2bf(a[1] + bv4.y);
                pk.z = f2bf(a[2] + bv4.z);
                pk.w = f2bf(a[3] + bv4.w);
                *(ushort4*)&dst[(((size_t)bb * H + h) * N + ii) * D + d0] = pk;
            }
        }
    } else {
        #pragma unroll
        for (int yt = 0; yt < 4; yt++) {
            const int o = o0 + y0 + yt * 16 + col;
            const int h = o >> 6;
            const int d = o & 63;
            const float bs = bias[o];
            #pragma unroll
            for (int xt = 0; xt < 4; xt++) {
                const int m  = m0 + x0 + xt * 16 + quad * 4;
                const int bb = m >> 11;
                const int ib = m & (N - 1);
                f4v a = acc[xt * 4 + yt];
                ushort4 pk;
                pk.x = f2bf(a[0] + bs);
                pk.y = f2bf(a[1] + bs);
                pk.z = f2bf(a[2] + bs);
                pk.w = f2bf(a[3] + bs);
                *(ushort4*)&Vt[(((size_t)bb * H + h) * D + d) * N + ib] = pk;
            }
        }
    }
}

// ---------------------------------------------------------------------------
// Fused relative attention v7 — LDS-byte-minimized:
//  * BD redistributed: each wave computes Sb[all 64 rho][u in 32w..32w+32)
//    via mfma(rese-frag, qAll) -> rese read DIRECT from global (no Res LDS,
//    no ring, no Rb staging). One SbD serves both rel-shift branches.
//  * Transposed chain (q in lane&15): Sb writes aligned ushort4; P path
//    4 b64 writes + 2 b128 reads; scalar per-lane softmax sum; float4 out.
//  * K staged in LDS (shared 4x) w/ register prefetch; V direct from global.
//  * 2 barriers/tile.  Plain launch bounds (R5/R6: caps => spill collapse).
// grid: (N/64, H, B)  block: 256 (4 waves).
// ---------------------------------------------------------------------------
constexpr int SBS = 140;     // SbD row stride (elems); 6*col banking, 8B mult
constexpr int PSS = 76;      // PsT row stride (elems)

__global__ __launch_bounds__(256) void attn_mfma_kernel(
    const ushort_t* __restrict__ Qb, const ushort_t* __restrict__ Kb,
    const ushort_t* __restrict__ Vt, const ushort_t* __restrict__ rese,
    const float* __restrict__ rbe, const float* __restrict__ rwb_g,
    float* __restrict__ out)
{
    const int i0 = blockIdx.x * 64;
    const int h  = blockIdx.y;
    const int b  = blockIdx.z;
    const int bh = b * H + h;

    const ushort_t* Qbh   = Qb + (size_t)bh * N * D;
    const ushort_t* Kbh   = Kb + (size_t)bh * N * D;
    const ushort_t* Vbh   = Vt + (size_t)bh * D * N;    // [d][n]
    const ushort_t* reseh = rese + (size_t)h * SE * D;  // [s][d] extended
    const float*    rbeh  = rbe + (size_t)h * SE;

    __shared__ ushort_t Ks[64][72];          // 9216 B
    __shared__ ushort_t SbD[65 * SBS];       // 18200 B  [rho][u]
    __shared__ ushort_t PsT[4][16 * PSS];    // 9728 B   per-wave [q][key]

    const int t    = threadIdx.x;
    const int lane = t & 63;
    const int w    = t >> 6;
    const int quad = lane >> 4;
    const int col  = lane & 15;
    ushort_t* Psw = &PsT[w][0];

    // ---- init: all 64 q rows as B-frags (direct global), qw = own + rwb ----
    s8v qAll[4][2], qw[2];
    #pragma unroll
    for (int v = 0; v < 4; v++)
        #pragma unroll
        for (int ks = 0; ks < 2; ks++)
            qAll[v][ks] = *(const s8v*)
                &Qbh[(size_t)(i0 + v * 16 + col) * D + ks * 32 + quad * 8];
    #pragma unroll
    for (int ks = 0; ks < 2; ks++) {
        float4 ra  = *(const float4*)&rwb_g[h * D + ks * 32 + quad * 8];
        float4 rb4 = *(const float4*)&rwb_g[h * D + ks * 32 + quad * 8 + 4];
        const float rv[8] = {ra.x, ra.y, ra.z, ra.w, rb4.x, rb4.y, rb4.z, rb4.w};
        s8v qq;
        #pragma unroll
        for (int j = 0; j < 8; j++)
            qq[j] = (short)f2bf(bf2f(qAll[w][ks][j]) + rv[j]);
        qw[ks] = qq;
    }
    // q64 chunk for row-64 distributed dot (d = (lane&3)*16 .. +16)
    const int sub = lane & 3;
    s8v q64a = {0,0,0,0,0,0,0,0}, q64b = {0,0,0,0,0,0,0,0};
    if (i0 + 64 < N) {
        q64a = *(const s8v*)&Qbh[(size_t)(i0 + 64) * D + sub * 16];
        q64b = *(const s8v*)&Qbh[(size_t)(i0 + 64) * D + sub * 16 + 8];
    }

    // ---- prologue: stage K tile 0 ----
    #pragma unroll
    for (int e = 0; e < 2; e++) {
        const int idx = t + e * 256;
        const int r   = idx >> 3;
        const int d8  = (idx & 7) * 8;
        *(s8v*)&Ks[r][d8] = *(const s8v*)&Kbh[(size_t)r * D + d8];
    }

    f4v Oacc[4];
    #pragma unroll
    for (int dt = 0; dt < 4; dt++) Oacc[dt] = (f4v){0.f, 0.f, 0.f, 0.f};
    float lacc = 0.f;

    const int  sE   = 1984 - i0;        // rese row = j0 + sE + u
    const int  rowg = 16 * w + col;     // this lane's q row (local)
    const float ESC = 0.18033688011112042f;   // 0.125 * log2(e)

    #pragma unroll 1
    for (int s = 0; s < 32; ++s) {
        const int j0 = s * 64;
        __syncthreads();   // [A] K(s) + SbD-write-safety

        // ---- prefetch K(s+1) into regs ----
        s8v pk[2];
        if (s < 31) {
            #pragma unroll
            for (int e = 0; e < 2; e++) {
                const int idx = t + e * 256;
                pk[e] = *(const s8v*)
                    &Kbh[(size_t)(j0 + 64 + (idx >> 3)) * D + (idx & 7) * 8];
            }
        }

        // ---- rese A-frags + rbe for this wave's u-quarter (global) ----
        s8v rf[2][2];
        float4 rbv[2];
        #pragma unroll
        for (int tt = 0; tt < 2; tt++) {
            const long long srow = (long long)(j0 + sE + 32 * w + tt * 16 + col);
            #pragma unroll
            for (int ks = 0; ks < 2; ks++)
                rf[tt][ks] = *(const s8v*)&reseh[srow * D + ks * 32 + quad * 8];
            rbv[tt] = *(const float4*)
                &rbeh[(long long)(j0 + sE + 32 * w + tt * 16 + quad * 4)];
        }
        // row-64 inputs
        const long long s64 = (long long)(j0 + sE + 16 * w + (lane >> 2));
        s8v r64a = *(const s8v*)&reseh[s64 * D + sub * 16];
        s8v r64b = *(const s8v*)&reseh[s64 * D + sub * 16 + 8];
        const float rb64 = rbeh[s64];

        // ---- AC (S^T): acc[tile] = (key = tile*16+quad*4+reg, q = col) ----
        f4v acc[4];
        #pragma unroll
        for (int tile = 0; tile < 4; tile++) {
            s8v kb0 = *(s8v*)&Ks[tile * 16 + col][quad * 8];
            s8v kb1 = *(s8v*)&Ks[tile * 16 + col][32 + quad * 8];
            acc[tile] = mfma16(kb0, qw[0], (f4v){0.f, 0.f, 0.f, 0.f});
            acc[tile] = mfma16(kb1, qw[1], acc[tile]);
        }

        // ---- Sb: all 64 rho x u-quarter; aligned ushort4 writes ----
        #pragma unroll
        for (int tt = 0; tt < 2; tt++) {
            #pragma unroll
            for (int v = 0; v < 4; v++) {
                f4v sb = mfma16(rf[tt][0], qAll[v][0], (f4v){0.f, 0.f, 0.f, 0.f});
                sb = mfma16(rf[tt][1], qAll[v][1], sb);
                ushort4 pa;
                pa.x = f2bf(sb[0] + rbv[tt].x);
                pa.y = f2bf(sb[1] + rbv[tt].y);
                pa.z = f2bf(sb[2] + rbv[tt].z);
                pa.w = f2bf(sb[3] + rbv[tt].w);
                *(ushort4*)&SbD[(v * 16 + col) * SBS + 32 * w + tt * 16 + quad * 4] = pa;
            }
        }
        // ---- row 64 (distributed dot over 4-lane groups) ----
        {
            float part = 0.f;
            #pragma unroll
            for (int j = 0; j < 8; j++) {
                part += bf2f(q64a[j]) * bf2f(r64a[j]);
                part += bf2f(q64b[j]) * bf2f(r64b[j]);
            }
            part += __shfl_xor(part, 1, 64);
            part += __shfl_xor(part, 2, 64);
            if (sub == 0)
                SbD[64 * SBS + 16 * w + (lane >> 2)] = f2bf(part + rb64);
        }
        __syncthreads();   // [B] SbD complete; Ks reads done

        // ---- V fragments (global, A-operand) ----
        s8v vfr[4][2];
        #pragma unroll
        for (int dt = 0; dt < 4; dt++)
            #pragma unroll
            for (int ks = 0; ks < 2; ks++)
                vfr[dt][ks] = *(const s8v*)
                    &Vbh[(size_t)(dt * 16 + col) * N + j0 + ks * 32 + quad * 8];

        // ---- gather (rel_shift) + no-max softmax -> PsT ----
        const ushort_t* rowA = &SbD[rowg * SBS];
        const ushort_t* rowB = &SbD[(rowg + 1) * SBS];
        #pragma unroll
        for (int tile = 0; tile < 4; tile++) {
            const int cpb = tile * 16 + quad * 4;
            const int ua  = cpb - rowg + 64;          // [1,124]
            const int T0  = j0 + cpb - i0 - rowg;     // trel at reg 0
            const int oa  = ua & 3;
            ull_t A0 = *(const ull_t*)&rowA[ua & ~3];
            ull_t A1 = *(const ull_t*)&rowA[(ua & ~3) + 4];
            ull_t valA = oa ? ((A0 >> (16 * oa)) | (A1 << (64 - 16 * oa))) : A0;
            const int ub = ua - 1;
            const int ob = ub & 3;
            ull_t B0 = *(const ull_t*)&rowB[ub & ~3];
            ull_t B1 = *(const ull_t*)&rowB[(ub & ~3) + 4];
            ull_t valB = ob ? ((B0 >> (16 * ob)) | (B1 << (64 - 16 * ob))) : B0;
            float pv4[4];
            #pragma unroll
            for (int reg = 0; reg < 4; reg++) {
                const int trel = T0 + reg;
                const unsigned short va = (unsigned short)(valA >> (16 * reg));
                const unsigned short vb = (unsigned short)(valB >> (16 * reg));
                float bd = (trel <= 0) ? bf2f((short)va)
                         : ((trel == 1) ? 0.f : bf2f((short)vb));
                const float e = __builtin_exp2f((acc[tile][reg] + bd) * ESC);
                pv4[reg] = e;
                lacc += e;
            }
            ushort4 pp;
            pp.x = f2bf(pv4[0]); pp.y = f2bf(pv4[1]);
            pp.z = f2bf(pv4[2]); pp.w = f2bf(pv4[3]);
            *(ushort4*)&Psw[col * PSS + cpb] = pp;
        }
        __asm__ volatile("s_waitcnt lgkmcnt(0)" ::: "memory");

        // ---- PV: O^T += V-frag x P^T-frag ----
        s8v pf0 = *(s8v*)&Psw[col * PSS + quad * 8];
        s8v pf1 = *(s8v*)&Psw[col * PSS + 32 + quad * 8];
        #pragma unroll
        for (int dt = 0; dt < 4; dt++) {
            Oacc[dt] = mfma16(vfr[dt][0], pf0, Oacc[dt]);
            Oacc[dt] = mfma16(vfr[dt][1], pf1, Oacc[dt]);
        }

        // ---- write prefetched K(s+1) (visible at next [A]) ----
        if (s < 31) {
            #pragma unroll
            for (int e = 0; e < 2; e++) {
                const int idx = t + e * 256;
                *(s8v*)&Ks[idx >> 3][(idx & 7) * 8] = pk[e];
            }
        }
    }

    // ---- final l reduction (4 quads share q=col) + epilogue ----
    lacc += __shfl_xor(lacc, 16, 64);
    lacc += __shfl_xor(lacc, 32, 64);
    const float inv = 1.f / lacc;
    const size_t base = ((size_t)b * N + (i0 + rowg)) * HID + h * D;
    #pragma unroll
    for (int dt = 0; dt < 4; dt++) {
        float4 o4;
        o4.x = Oacc[dt][0] * inv;
        o4.y = Oacc[dt][1] * inv;
        o4.z = Oacc[dt][2] * inv;
        o4.w = Oacc[dt][3] * inv;
        *(float4*)&out[base + dt * 16 + quad * 4] = o4;
    }
}

// ---------------------------------------------------------------------------
extern "C" void kernel_launch(void* const* d_in, const int* in_sizes, int n_in,
                              void* d_out, int out_size, void* d_ws, size_t ws_size,
                              hipStream_t stream)
{
    (void)in_sizes; (void)n_in; (void)out_size; (void)ws_size;
    const float* hs   = (const float*)d_in[0];
    const float* remb = (const float*)d_in[1];
    const float* rwb  = (const float*)d_in[2];
    const float* rb   = (const float*)d_in[3];
    const float* Wq   = (const float*)d_in[4];
    const float* bq   = (const float*)d_in[5];
    const float* Wk   = (const float*)d_in[6];
    const float* bk   = (const float*)d_in[7];
    const float* Wv   = (const float*)d_in[8];
    const float* bv   = (const float*)d_in[9];
    float* out = (float*)d_out;

    ushort_t* Qb   = (ushort_t*)d_ws;
    ushort_t* Kb   = Qb + QKV_ELEMS;
    ushort_t* Vt   = Kb + QKV_ELEMS;
    ushort_t* rese = Vt + QKV_ELEMS;              // H*SE*D
    float*    rbe  = (float*)(rese + H * SE * D); // H*SE
    ushort_t* hsb  = (ushort_t*)(rbe + H * SE);
    ushort_t* Wb   = hsb + (size_t)M * HID;

    convert_kernel<<<CVT_C3 / 256, 256, 0, stream>>>(
        hs, Wq, Wk, Wv, remb, rb, hsb, Wb, rese, rbe);
    qkv_mfma_kernel<<<dim3(M / 128, HID / 128, 3), 256, 0, stream>>>(
        hsb, Wb, bq, bk, bv, Qb, Kb, Vt);
    attn_mfma_kernel<<<dim3(N / 64, H, B), 256, 0, stream>>>(
        Qb, Kb, Vt, rese, rbe, rwb, out);
}